// Round 5
// baseline (71.897 us; speedup 1.0000x reference)
//
#include <hip/hip_runtime.h>
#include <hip/hip_bf16.h>

#define B_ 2
#define H_ 16
#define S_ 2048
#define D_ 64

typedef __attribute__((ext_vector_type(8))) short bf16x8;
typedef __attribute__((ext_vector_type(8))) unsigned short u16x8;
typedef __attribute__((ext_vector_type(16))) float f32x16;
typedef __attribute__((ext_vector_type(4))) float f32x4v;
typedef __attribute__((ext_vector_type(4))) unsigned int u32x4;
typedef unsigned short ushort_t;

#define SCALE 0.18033688011112042f  // (1/sqrt(64)) * log2(e)

__device__ __forceinline__ unsigned short f2bf(float x) {
  unsigned int u = __builtin_bit_cast(unsigned int, x);
  unsigned int r = (u + 0x7FFFu + ((u >> 16) & 1u)) >> 16;
  return (unsigned short)r;
}

__device__ __forceinline__ unsigned int cvt_pk_bf16(float lo, float hi) {
  unsigned int r;
  asm("v_cvt_pk_bf16_f32 %0, %1, %2" : "=v"(r) : "v"(lo), "v"(hi));
  return r;
}

__device__ __forceinline__ float vmax16(f32x16 v) {
  float a = fmaxf(fmaxf(v[0], v[1]), fmaxf(v[2], v[3]));
  float b = fmaxf(fmaxf(v[4], v[5]), fmaxf(v[6], v[7]));
  float c = fmaxf(fmaxf(v[8], v[9]), fmaxf(v[10], v[11]));
  float d = fmaxf(fmaxf(v[12], v[13]), fmaxf(v[14], v[15]));
  return fmaxf(fmaxf(a, b), fmaxf(c, d));
}
__device__ __forceinline__ float vsum16(f32x16 v) {
  float a = (v[0] + v[1]) + (v[2] + v[3]);
  float b = (v[4] + v[5]) + (v[6] + v[7]);
  float c = (v[8] + v[9]) + (v[10] + v[11]);
  float d = (v[12] + v[13]) + (v[14] + v[15]);
  return (a + b) + (c + d);
}

#define GLL16(gp, lp)                                                          \
  __builtin_amdgcn_global_load_lds(                                            \
      (const __attribute__((address_space(1))) unsigned int*)(gp),             \
      (__attribute__((address_space(3))) unsigned int*)(lp), 16, 0, 0)

// ---------------- prepass: K/V fp32 -> bf16, swizzle + row-permute baked ----
// K tile (per bh,t; 4096 ushorts): addr e: LDS row rl=e>>6, pos=(e>>3)&7,
//   chunk ch = pos ^ (rl&7); SOURCE row = tau(rl) = rl with bits2<->3 swapped.
//   content = K[t*64 + tau(rl)][ch*8 + i]
// The bit2<->3 swap makes the QK^T 32x32 D-layout coincide with the PV
// B-fragment layout (zero cross-lane exchange for P).
// Vt tile: d=e>>6 -> content = V[t*64 + (pos^(d&7))*8 + i][d]  (kv NOT permuted)
__global__ void prepack(const float* __restrict__ Kf, const float* __restrict__ Vf,
                        ushort_t* __restrict__ Kg, ushort_t* __restrict__ Vtg) {
  const int blk = blockIdx.x;  // bh*32 + t
  const int tid = threadIdx.x;
  const int bh = blk >> 5, t = blk & 31;
  const float* srcK = Kf + ((size_t)bh * S_ + (size_t)t * 64) * D_;
  const float* srcV = Vf + ((size_t)bh * S_ + (size_t)t * 64) * D_;
  ushort_t* dK = Kg + (size_t)blk * 4096;
  ushort_t* dV = Vtg + (size_t)blk * 4096;
  for (int is = 0; is < 2; ++is) {
    const int e = is * 2048 + tid * 8;
    {  // K with row permute
      const int rl = e >> 6, pos = (e >> 3) & 7, ch = pos ^ (rl & 7);
      const int kvs = (rl & 51) | ((rl & 4) << 1) | ((rl & 8) >> 1);  // swap b2<->b3
      const float* sp = srcK + kvs * 64 + ch * 8;
      float4 a = *(const float4*)sp;
      float4 b = *(const float4*)(sp + 4);
      u16x8 w;
      w[0] = f2bf(a.x); w[1] = f2bf(a.y); w[2] = f2bf(a.z); w[3] = f2bf(a.w);
      w[4] = f2bf(b.x); w[5] = f2bf(b.y); w[6] = f2bf(b.z); w[7] = f2bf(b.w);
      *(u16x8*)(dK + e) = w;
    }
    {  // V transposed
      const int d0 = e >> 6, pos = (e >> 3) & 7, ch = pos ^ (d0 & 7);
      u16x8 w;
      for (int i = 0; i < 8; ++i) w[i] = f2bf(srcV[(size_t)(ch * 8 + i) * 64 + d0]);
      *(u16x8*)(dV + e) = w;
    }
  }
}

// ---------------- hot kernel: 32x32 swapped-QK^T flash attention ------------
// 2 waves/block; wave wq owns q rows qt*64 + wq*32 + (lane&31).
// S^T = K~ . Q^T via mfma_32x32x16 (K~ = row-permuted K in LDS).
// PV B-frag = cvt_pk'd s words directly (layout aligned by the row permute).
template <int PRE>
__launch_bounds__(128, 3)
__global__ void attn5(const float* __restrict__ Qf, const float* __restrict__ Kf,
                      const float* __restrict__ Vf, const ushort_t* __restrict__ Kg,
                      const ushort_t* __restrict__ Vtg, float* __restrict__ O) {
  const int bh = blockIdx.x;       // 0..31
  const int qt = 31 - blockIdx.y;  // longest blocks dispatched first
  const int tid = threadIdx.x;
  const int wq = tid >> 6, lane = tid & 63;
  const int cq = lane & 31, hi = lane >> 5;

  __shared__ __align__(16) ushort_t Kl[2][64][64];
  __shared__ __align__(16) ushort_t Vt[2][64][64];

  const int qrow = qt * 64 + wq * 32 + cq;

  // Q B-frag: qf[ks] = Q[qrow][ks*16 + 8*hi + i], i=0..7 (scaled)
  bf16x8 qf[4];
  {
    const float* qp = Qf + (size_t)bh * S_ * D_ + (size_t)qrow * D_ + 8 * hi;
    #pragma unroll
    for (int ks = 0; ks < 4; ++ks) {
      float4 a = *(const float4*)(qp + ks * 16);
      float4 b = *(const float4*)(qp + ks * 16 + 4);
      bf16x8 w;
      w[0] = (short)f2bf(a.x * SCALE); w[1] = (short)f2bf(a.y * SCALE);
      w[2] = (short)f2bf(a.z * SCALE); w[3] = (short)f2bf(a.w * SCALE);
      w[4] = (short)f2bf(b.x * SCALE); w[5] = (short)f2bf(b.y * SCALE);
      w[6] = (short)f2bf(b.z * SCALE); w[7] = (short)f2bf(b.w * SCALE);
      qf[ks] = w;
    }
  }

  f32x16 acc0 = {}, acc1 = {};
  float m_ = -INFINITY, l_ = 0.0f;
  const int chA = cq & 7;  // xor key for LDS rows cq and 32+cq

  auto STAGE = [&](int t, int b) {
    if (PRE) {
      const ushort_t* kg = Kg + ((size_t)(bh * 32 + t)) * 4096;
      const ushort_t* vg = Vtg + ((size_t)(bh * 32 + t)) * 4096;
      ushort_t* kl = &Kl[b][0][0];
      ushort_t* vl = &Vt[b][0][0];
      #pragma unroll
      for (int j = 0; j < 4; ++j) {
        GLL16(kg + j * 1024 + tid * 8, kl + j * 1024 + tid * 8);
        GLL16(vg + j * 1024 + tid * 8, vl + j * 1024 + tid * 8);
      }
    } else {
      const float* Kh = Kf + (size_t)bh * S_ * D_;
      const float* Vh = Vf + (size_t)bh * S_ * D_;
      {  // K rows (with permute), 2 threads per row
        const int rl = tid >> 1, h = tid & 1;
        const int kvs = (rl & 51) | ((rl & 4) << 1) | ((rl & 8) >> 1);
        const float* src = Kh + ((size_t)(t * 64 + kvs)) * 64 + h * 32;
        #pragma unroll
        for (int jj = 0; jj < 4; ++jj) {
          float4 x = *(const float4*)(src + jj * 8);
          float4 y = *(const float4*)(src + jj * 8 + 4);
          u16x8 w;
          w[0] = f2bf(x.x); w[1] = f2bf(x.y); w[2] = f2bf(x.z); w[3] = f2bf(x.w);
          w[4] = f2bf(y.x); w[5] = f2bf(y.y); w[6] = f2bf(y.z); w[7] = f2bf(y.w);
          const int ch = h * 4 + jj;
          *(u16x8*)&Kl[b][rl][(ch ^ (rl & 7)) << 3] = w;
        }
      }
      {  // V transposed: column strips
        const int c = tid & 63, rh = tid >> 6;
        const float* sv = Vh + ((size_t)t * 64) * 64 + c;
        #pragma unroll
        for (int jj = 0; jj < 4; ++jj) {
          const int ch = rh * 4 + jj;
          u16x8 w;
          for (int i = 0; i < 8; ++i) w[i] = f2bf(sv[(size_t)(ch * 8 + i) * 64]);
          *(u16x8*)&Vt[b][c][(ch ^ (c & 7)) << 3] = w;
        }
      }
    }
  };

  auto COMPUTE = [&](int b, bool diag) {
    // S^T rows live in permuted lr-space; lane holds 32 values for q-col cq.
    f32x16 s0 = {}, s1 = {};
    __builtin_amdgcn_s_setprio(1);
    #pragma unroll
    for (int ks = 0; ks < 4; ++ks) {
      const int co = (((ks << 1) | hi) ^ chA) << 3;
      const bf16x8 k0 = *(const bf16x8*)&Kl[b][cq][co];
      const bf16x8 k1 = *(const bf16x8*)&Kl[b][32 + cq][co];
      s0 = __builtin_amdgcn_mfma_f32_32x32x16_bf16(k0, qf[ks], s0, 0, 0, 0);
      s1 = __builtin_amdgcn_mfma_f32_32x32x16_bf16(k1, qf[ks], s1, 0, 0, 0);
    }
    __builtin_amdgcn_s_setprio(0);

    if (diag) {  // actual kv of reg r = tau(lr): 16*(r>>3) + 8*hi + 4*((r>>2)&1) + (r&3)
      const int qloc = wq * 32 + cq;
      #pragma unroll
      for (int r = 0; r < 16; ++r) {
        const int tau = 16 * (r >> 3) + 4 * ((r >> 2) & 1) + (r & 3) + 8 * hi;
        if (tau > qloc) s0[r] = -INFINITY;
        if (32 + tau > qloc) s1[r] = -INFINITY;
      }
    }

    // online softmax: 32 in-lane values + partner lane (hi^1) via one shfl
    float pm = fmaxf(vmax16(s0), vmax16(s1));
    pm = fmaxf(pm, __shfl_xor(pm, 32));
    float fac = 1.0f;
    if (!__all(pm - m_ <= 8.0f)) {  // defer-max (T13)
      const float mn = fmaxf(m_, pm);
      fac = exp2f(m_ - mn);
      m_ = mn;
      #pragma unroll
      for (int r = 0; r < 16; ++r) { acc0[r] *= fac; acc1[r] *= fac; }
    }
    #pragma unroll
    for (int r = 0; r < 16; ++r) {
      s0[r] = exp2f(s0[r] - m_);
      s1[r] = exp2f(s1[r] - m_);
    }
    float sum = vsum16(s0) + vsum16(s1);
    sum += __shfl_xor(sum, 32);
    l_ = l_ * fac + sum;

    // P -> bf16 words; thanks to the row permute these ARE the PV B-frags
    unsigned W0[8], W1[8];
    #pragma unroll
    for (int j = 0; j < 8; ++j) {
      W0[j] = cvt_pk_bf16(s0[2 * j], s0[2 * j + 1]);
      W1[j] = cvt_pk_bf16(s1[2 * j], s1[2 * j + 1]);
    }

    __builtin_amdgcn_s_setprio(1);
#define PVSTEP(ks, Wm)                                                         \
    {                                                                          \
      u32x4 t4;                                                                \
      t4[0] = Wm[4 * ((ks) & 1) + 0]; t4[1] = Wm[4 * ((ks) & 1) + 1];          \
      t4[2] = Wm[4 * ((ks) & 1) + 2]; t4[3] = Wm[4 * ((ks) & 1) + 3];          \
      const bf16x8 pf = __builtin_bit_cast(bf16x8, t4);                        \
      const int co = ((((ks) << 1) | hi) ^ chA) << 3;                          \
      const bf16x8 v0 = *(const bf16x8*)&Vt[b][cq][co];                        \
      const bf16x8 v1 = *(const bf16x8*)&Vt[b][32 + cq][co];                   \
      acc0 = __builtin_amdgcn_mfma_f32_32x32x16_bf16(v0, pf, acc0, 0, 0, 0);   \
      acc1 = __builtin_amdgcn_mfma_f32_32x32x16_bf16(v1, pf, acc1, 0, 0, 0);   \
    }
    PVSTEP(0, W0) PVSTEP(1, W0) PVSTEP(2, W1) PVSTEP(3, W1)
#undef PVSTEP
    __builtin_amdgcn_s_setprio(0);
  };

  int cur = 0;
  STAGE(0, 0);
  __syncthreads();
  for (int t = 0; t <= qt; ++t) {
    if (t < qt) STAGE(t + 1, cur ^ 1);
    COMPUTE(cur, t == qt);
    __syncthreads();
    cur ^= 1;
  }

  // epilogue: lane holds O^T[d = dt*32 + 8*q2 + 4*hi + e][qrow]
  const float inv = 1.0f / l_;
  float* dst = O + (size_t)bh * S_ * D_ + (size_t)qrow * D_;
  #pragma unroll
  for (int q2 = 0; q2 < 4; ++q2) {
    f32x4v v0, v1;
    #pragma unroll
    for (int e = 0; e < 4; ++e) {
      v0[e] = acc0[4 * q2 + e] * inv;
      v1[e] = acc1[4 * q2 + e] * inv;
    }
    *(f32x4v*)(dst + 8 * q2 + 4 * hi) = v0;
    *(f32x4v*)(dst + 32 + 8 * q2 + 4 * hi) = v1;
  }
}

extern "C" void kernel_launch(void* const* d_in, const int* in_sizes, int n_in,
                              void* d_out, int out_size, void* d_ws, size_t ws_size,
                              hipStream_t stream) {
  const float* Q = (const float*)d_in[0];
  const float* K = (const float*)d_in[1];
  const float* V = (const float*)d_in[2];
  float* O = (float*)d_out;
  const size_t NE = (size_t)B_ * H_ * S_ * D_;  // 4194304
  if (ws_size >= 2 * NE * sizeof(ushort_t)) {
    ushort_t* kg = (ushort_t*)d_ws;
    prepack<<<1024, 256, 0, stream>>>(K, V, kg, kg + NE);
    attn5<1><<<dim3(32, 32), 128, 0, stream>>>(Q, K, V, kg, kg + NE, O);
  } else {
    attn5<0><<<dim3(32, 32), 128, 0, stream>>>(Q, K, V, nullptr, nullptr, O);
  }
}

// Round 6
// 58.368 us; speedup vs baseline: 1.2318x; 1.2318x over previous
//
#include <hip/hip_runtime.h>
#include <hip/hip_bf16.h>

#define B_ 2
#define H_ 16
#define S_ 2048
#define D_ 64

typedef __attribute__((ext_vector_type(8))) short bf16x8;
typedef __attribute__((ext_vector_type(8))) unsigned short u16x8;
typedef __attribute__((ext_vector_type(4))) unsigned int u32x4;
typedef __attribute__((ext_vector_type(4))) float f32x4;
typedef unsigned short ushort_t;

#define SCALE 0.18033688011112042f  // (1/sqrt(64)) * log2(e)

__device__ __forceinline__ unsigned short f2bf(float x) {
  unsigned int u = __builtin_bit_cast(unsigned int, x);
  unsigned int r = (u + 0x7FFFu + ((u >> 16) & 1u)) >> 16;
  return (unsigned short)r;
}

__device__ __forceinline__ unsigned int cvt_pk_bf16(float lo, float hi) {
  unsigned int r;
  asm("v_cvt_pk_bf16_f32 %0, %1, %2" : "=v"(r) : "v"(lo), "v"(hi));
  return r;
}

// sigma: LDS row rl holds K row sigma(rl); bit permute (b5 b4 b3 b2 b1 b0) ->
// (b5 b3 b2 b4 b1 b0). Makes QK^T D-layout == PV B-frag order (P stays in reg).
__device__ __forceinline__ int sigma_row(int rl) {
  return (rl & 0x23) | ((rl & 0x0C) << 1) | ((rl & 0x10) >> 2);
}

#define GLL16(gp, lp)                                                          \
  __builtin_amdgcn_global_load_lds(                                            \
      (const __attribute__((address_space(1))) unsigned int*)(gp),             \
      (__attribute__((address_space(3))) unsigned int*)(lp), 16, 0, 0)

// ---------------- prepass: K/V fp32 -> bf16, swizzle + K-row-permute baked --
// K tile (per bh,t; 4096 ushorts): addr e: LDS row rl=e>>6, pos=(e>>3)&7,
//   chunk ch = pos ^ (rl&7); content = K[t*64 + sigma(rl)][ch*8 + i]
// Vt tile: d=e>>6 -> content = V[t*64 + (pos^(d&7))*8 + i][d]
__global__ void prepack(const float* __restrict__ Kf, const float* __restrict__ Vf,
                        ushort_t* __restrict__ Kg, ushort_t* __restrict__ Vtg) {
  const int blk = blockIdx.x;  // bh*32 + t
  const int tid = threadIdx.x;
  const int bh = blk >> 5, t = blk & 31;
  const float* srcK = Kf + ((size_t)bh * S_ + (size_t)t * 64) * D_;
  const float* srcV = Vf + ((size_t)bh * S_ + (size_t)t * 64) * D_;
  ushort_t* dK = Kg + (size_t)blk * 4096;
  ushort_t* dV = Vtg + (size_t)blk * 4096;
  for (int is = 0; is < 2; ++is) {
    const int e = is * 2048 + tid * 8;
    {  // K with sigma row permute
      const int rl = e >> 6, pos = (e >> 3) & 7, ch = pos ^ (rl & 7);
      const float* sp = srcK + sigma_row(rl) * 64 + ch * 8;
      float4 a = *(const float4*)sp;
      float4 b = *(const float4*)(sp + 4);
      u16x8 w;
      w[0] = f2bf(a.x); w[1] = f2bf(a.y); w[2] = f2bf(a.z); w[3] = f2bf(a.w);
      w[4] = f2bf(b.x); w[5] = f2bf(b.y); w[6] = f2bf(b.z); w[7] = f2bf(b.w);
      *(u16x8*)(dK + e) = w;
    }
    {  // V transposed
      const int d0 = e >> 6, pos = (e >> 3) & 7, ch = pos ^ (d0 & 7);
      u16x8 w;
      for (int i = 0; i < 8; ++i) w[i] = f2bf(srcV[(size_t)(ch * 8 + i) * 64 + d0]);
      *(u16x8*)(dV + e) = w;
    }
  }
}

// ---------------- hot kernel: swapped-QK^T flash attention, P in registers --
template <int PRE>
__launch_bounds__(256, 4)
__global__ void attn6(const float* __restrict__ Qf, const float* __restrict__ Kf,
                      const float* __restrict__ Vf, const ushort_t* __restrict__ Kg,
                      const ushort_t* __restrict__ Vtg, float* __restrict__ O) {
  const int bh = blockIdx.x;          // 0..31
  const int qt = 31 - blockIdx.y;     // LPT: longest blocks first
  const int tid = threadIdx.x;
  const int wave = tid >> 6, lane = tid & 63;
  const int col = lane & 15, g = lane >> 4;

  __shared__ __align__(16) ushort_t Kl[2][64][64];
  __shared__ __align__(16) ushort_t Vt[2][64][64];

  float* Oh = O + (size_t)bh * S_ * D_;

  // ---- Q fragment (one-time): lane holds Q[qrow][32kk+8g+i] ----
  const int qrow = qt * 64 + wave * 16 + col;
  bf16x8 qf[2];
  {
    const float* Qh = Qf + (size_t)bh * S_ * D_;
    for (int kk = 0; kk < 2; ++kk) {
      const float* p = Qh + (size_t)qrow * 64 + kk * 32 + g * 8;
      float4 a = *(const float4*)p;
      float4 b = *(const float4*)(p + 4);
      float v[8] = {a.x, a.y, a.z, a.w, b.x, b.y, b.z, b.w};
      bf16x8 w;
      for (int i = 0; i < 8; ++i) w[i] = (short)f2bf(v[i] * SCALE);
      qf[kk] = w;
    }
  }

  f32x4 acc[4] = {};
  float m_ = -INFINITY, l_ = 0.0f;

  // per-lane constant LDS chunk byte offsets (XOR key = col&7 for rows nt*16+col)
  const int ch0 = (g ^ (col & 7)) << 3;
  const int ch1 = ((4 | g) ^ (col & 7)) << 3;

  auto STAGE = [&](int t, int b) {
    if (PRE) {
      const ushort_t* kg = Kg + ((size_t)(bh * 32 + t)) * 4096;
      const ushort_t* vg = Vtg + ((size_t)(bh * 32 + t)) * 4096;
      GLL16(kg + tid * 8,        &Kl[b][0][0] + tid * 8);
      GLL16(kg + 2048 + tid * 8, &Kl[b][0][0] + 2048 + tid * 8);
      GLL16(vg + tid * 8,        &Vt[b][0][0] + tid * 8);
      GLL16(vg + 2048 + tid * 8, &Vt[b][0][0] + 2048 + tid * 8);
    } else {
      const float* Kh = Kf + (size_t)bh * S_ * D_;
      const float* Vh = Vf + (size_t)bh * S_ * D_;
      {  // K rows (sigma-permuted), coalesced
        const int rl = tid >> 2;
        const int c0 = (tid & 3) << 4;
        const float* src = Kh + ((size_t)(t * 64 + sigma_row(rl))) * 64 + c0;
        for (int jj = 0; jj < 2; ++jj) {
          float4 x = *(const float4*)(src + jj * 8);
          float4 y = *(const float4*)(src + jj * 8 + 4);
          u16x8 w;
          w[0] = f2bf(x.x); w[1] = f2bf(x.y); w[2] = f2bf(x.z); w[3] = f2bf(x.w);
          w[4] = f2bf(y.x); w[5] = f2bf(y.y); w[6] = f2bf(y.z); w[7] = f2bf(y.w);
          const int ch = (c0 >> 3) + jj;
          *(u16x8*)&Kl[b][rl][(ch ^ (rl & 7)) << 3] = w;
        }
      }
      {  // V column strips -> transposed
        const int c = tid & 63;
        const int r0 = (tid >> 6) << 4;
        const float* src = Vh + ((size_t)(t * 64 + r0)) * 64 + c;
        for (int jj = 0; jj < 2; ++jj) {
          u16x8 w;
          for (int i = 0; i < 8; ++i) w[i] = f2bf(src[(size_t)(jj * 8 + i) * 64]);
          const int ch = (r0 >> 3) + jj;
          *(u16x8*)&Vt[b][c][(ch ^ (c & 7)) << 3] = w;
        }
      }
    }
  };

  auto COMPUTE = [&](int b, bool diag) {
    // S^T (sigma-permuted rows): s[nt][r] = S^T[sigma(16nt+4g+r)][qrow]
    f32x4 s[4] = {{0,0,0,0},{0,0,0,0},{0,0,0,0},{0,0,0,0}};
    __builtin_amdgcn_s_setprio(1);
    for (int nt = 0; nt < 4; ++nt) {
      const ushort_t* row = &Kl[b][nt * 16 + col][0];
      const bf16x8 kf0 = *(const bf16x8*)(row + ch0);
      const bf16x8 kf1 = *(const bf16x8*)(row + ch1);
      s[nt] = __builtin_amdgcn_mfma_f32_16x16x32_bf16(kf0, qf[0], s[nt], 0, 0, 0);
      s[nt] = __builtin_amdgcn_mfma_f32_16x16x32_bf16(kf1, qf[1], s[nt], 0, 0, 0);
    }
    __builtin_amdgcn_s_setprio(0);
    if (diag) {
      const int qloc = wave * 16 + col;
      #pragma unroll
      for (int nt = 0; nt < 4; ++nt) {
        const int tau_base = 32 * (nt >> 1) + 4 * (nt & 1) + 8 * g;  // + r
        #pragma unroll
        for (int r = 0; r < 4; ++r)
          if (tau_base + r > qloc) s[nt][r] = -INFINITY;
      }
    }
    // row max: 16 in-lane, then combine the 4 g-lanes of this q-row
    float pm = fmaxf(fmaxf(fmaxf(s[0][0], s[0][1]), fmaxf(s[0][2], s[0][3])),
                     fmaxf(fmaxf(s[1][0], s[1][1]), fmaxf(s[1][2], s[1][3])));
    pm = fmaxf(pm, fmaxf(fmaxf(fmaxf(s[2][0], s[2][1]), fmaxf(s[2][2], s[2][3])),
                         fmaxf(fmaxf(s[3][0], s[3][1]), fmaxf(s[3][2], s[3][3]))));
    pm = fmaxf(pm, __shfl_xor(pm, 16));
    pm = fmaxf(pm, __shfl_xor(pm, 32));
    float fac = 1.0f;
    if (!__all(pm - m_ <= 8.0f)) {  // defer-max (T13)
      const float mn = fmaxf(m_, pm);
      fac = exp2f(m_ - mn);
      m_ = mn;
      for (int nt = 0; nt < 4; ++nt) acc[nt] *= fac;
    }
    float sum = 0.0f;
    for (int nt = 0; nt < 4; ++nt)
      for (int r = 0; r < 4; ++r) {
        const float p = exp2f(s[nt][r] - m_);
        s[nt][r] = p;
        sum += p;
      }
    sum += __shfl_xor(sum, 16);
    sum += __shfl_xor(sum, 32);
    l_ = l_ * fac + sum;
    // P fragments directly from registers (sigma made the layouts coincide)
    u32x4 t0, t1;
    t0[0] = cvt_pk_bf16(s[0][0], s[0][1]); t0[1] = cvt_pk_bf16(s[0][2], s[0][3]);
    t0[2] = cvt_pk_bf16(s[1][0], s[1][1]); t0[3] = cvt_pk_bf16(s[1][2], s[1][3]);
    t1[0] = cvt_pk_bf16(s[2][0], s[2][1]); t1[1] = cvt_pk_bf16(s[2][2], s[2][3]);
    t1[2] = cvt_pk_bf16(s[3][0], s[3][1]); t1[3] = cvt_pk_bf16(s[3][2], s[3][3]);
    const bf16x8 pf0 = __builtin_bit_cast(bf16x8, t0);
    const bf16x8 pf1 = __builtin_bit_cast(bf16x8, t1);
    // O^T += V^T · P^T
    __builtin_amdgcn_s_setprio(1);
    for (int nt = 0; nt < 4; ++nt) {
      const ushort_t* row = &Vt[b][nt * 16 + col][0];
      const bf16x8 vf0 = *(const bf16x8*)(row + ch0);
      const bf16x8 vf1 = *(const bf16x8*)(row + ch1);
      acc[nt] = __builtin_amdgcn_mfma_f32_16x16x32_bf16(vf0, pf0, acc[nt], 0, 0, 0);
      acc[nt] = __builtin_amdgcn_mfma_f32_16x16x32_bf16(vf1, pf1, acc[nt], 0, 0, 0);
    }
    __builtin_amdgcn_s_setprio(0);
  };

  int cur = 0;
  STAGE(0, 0);
  __syncthreads();
  for (int t = 0; t <= qt; ++t) {
    if (t < qt) STAGE(t + 1, cur ^ 1);
    COMPUTE(cur, t == qt);
    __syncthreads();
    cur ^= 1;
  }

  // ---- epilogue: lane holds O^T[d=nt*16+4g+r][qrow] ----
  const float inv = 1.0f / l_;
  float* dst = Oh + (size_t)qrow * 64;
  for (int nt = 0; nt < 4; ++nt) {
    f32x4 v = acc[nt];
    v *= inv;
    *(f32x4*)(dst + nt * 16 + 4 * g) = v;
  }
}

extern "C" void kernel_launch(void* const* d_in, const int* in_sizes, int n_in,
                              void* d_out, int out_size, void* d_ws, size_t ws_size,
                              hipStream_t stream) {
  const float* Q = (const float*)d_in[0];
  const float* K = (const float*)d_in[1];
  const float* V = (const float*)d_in[2];
  float* O = (float*)d_out;
  const size_t NE = (size_t)B_ * H_ * S_ * D_;  // 4194304
  if (ws_size >= 2 * NE * sizeof(ushort_t)) {
    ushort_t* kg = (ushort_t*)d_ws;
    prepack<<<1024, 256, 0, stream>>>(K, V, kg, kg + NE);
    attn6<1><<<dim3(32, 32), 256, 0, stream>>>(Q, K, V, kg, kg + NE, O);
  } else {
    attn6<0><<<dim3(32, 32), 256, 0, stream>>>(Q, K, V, nullptr, nullptr, O);
  }
}